// Round 3
// baseline (10327.343 us; speedup 1.0000x reference)
//
#include <hip/hip_runtime.h>

// LSTMAutoEncoder: B=64, T=512, H=512, F=32.
// Dead-code analysis: only encoder layer 0 (final h,c) and decoder layer 0
// feed the output: out[:, t, :] = h_dec0_before_step(511-t) @ W_out^T + b_out.
// -> 1024 sequential LSTM cell steps; batch split into 4 independent pods of
// 16 rows x 64 blocks (1 block/CU).
//
// Round 3 design:
//  - Weights in VGPRs (68 f32/thread = block's full 32x544 slice). No weight
//    LDS tile, no weight LDS reads in the K-loop -> GEMM ~1B/FMA from LDS.
//  - Per-lane XOR slice offsets (kk ^ (ks&7)) de-collide the 16 ks-lanes'
//    ds_read_b128 within each instruction (2-way max, free).
//  - Distributed flag barrier: one store/block (no RMW fan-in), one 64-lane
//    gather load to poll. Decoder out-projection runs AFTER the flag store,
//    hidden under peers' poll.
//  - h exchange: sc1 write-through stores + sc1 bypass loads (LLC-coherent),
//    parity double-buffer; c never leaves its register.

#define BB   64
#define TT   512
#define HH   512
#define FF   32
#define KP   548              // U row stride (floats): 512 h + 32 x + pad
#define PODS 4
#define BT   16               // batch rows per pod
#define GBLK 64               // blocks per pod
#define JT   8                // hidden indices per block
#define NTHR 256
#define NBLK (PODS * GBLK)
#define GRS  34               // Gr row stride (per batch row)
#define GPL  546              // Gr plane stride (per ks) = 16*34+2
#define U_FLOATS  (BT * KP)   // 8768
#define GR_FLOATS (16 * GPL)  // 8736
#define LDS_FLOATS (U_FLOATS + GR_FLOATS)
#define LDS_BYTES  (LDS_FLOATS * 4)
#define FLAG_STRIDE 128       // u32 per pod (512 B)

typedef float f4v __attribute__((ext_vector_type(4)));
typedef unsigned long long u64;

__device__ __forceinline__ float sigmf(float x)    { return 1.f / (1.f + __expf(-x)); }
__device__ __forceinline__ float tanhfast(float x) { return 1.f - 2.f / (__expf(2.f * x) + 1.f); }

// Load this thread's weight slice into registers. Thread (ks, gt) owns gate
// rows rA=gt, rB=gt+16 and K-slice [ks*32, ks*32+32) of Whh plus x-cols
// {ks*2, ks*2+1} of Wih. Register index is STATIC (kk*4+c); the visit-order
// XOR permutation lives in the (runtime) global address only.
__device__ __forceinline__ void load_w(
    const float* __restrict__ Wih, const float* __restrict__ Whh,
    const float* __restrict__ bih, const float* __restrict__ bhh,
    int j0, int ks, int gt, int p, float* wA, float* wB, float& bA, float& bB)
{
  const int rA = gt, rB = gt + 16;
  const int gA = (rA >> 3) * HH + j0 + (rA & 7);
  const int gB = (rB >> 3) * HH + j0 + (rB & 7);
  #pragma unroll
  for (int kk = 0; kk < 8; ++kk) {
    const int q = ((kk ^ p) << 2) + ks * 32;   // runtime addr, static reg idx
    #pragma unroll
    for (int c = 0; c < 4; ++c) {
      wA[kk * 4 + c] = Whh[gA * HH + q + c];
      wB[kk * 4 + c] = Whh[gB * HH + q + c];
    }
  }
  wA[32] = Wih[gA * FF + ks * 2]; wA[33] = Wih[gA * FF + ks * 2 + 1];
  wB[32] = Wih[gB * FF + ks * 2]; wB[33] = Wih[gB * FF + ks * 2 + 1];
  bA = bih[gA] + bhh[gA];
  bB = bih[gB] + bhh[gB];
}

__global__ void init_ws_kernel(float* hbuf, unsigned* flags) {
  const int i = blockIdx.x * blockDim.x + threadIdx.x;
  if (i < 2 * BB * HH) hbuf[i] = 0.f;
  if (i < PODS * FLAG_STRIDE) flags[i] = 0u;
}

__global__ void __launch_bounds__(NTHR, 1)
lstm_ae_kernel(const float* __restrict__ x,
               const float* __restrict__ eWih, const float* __restrict__ eWhh,
               const float* __restrict__ ebih, const float* __restrict__ ebhh,
               const float* __restrict__ dWih, const float* __restrict__ dWhh,
               const float* __restrict__ dbih, const float* __restrict__ dbhh,
               const float* __restrict__ Wo,  const float* __restrict__ bo,
               float* __restrict__ out, float* __restrict__ hbuf,
               unsigned* __restrict__ flags)
{
  extern __shared__ float lds[];
  float* U  = lds;               // [BT][KP]   h | x_t   (35 KB)
  float* Gr = lds + U_FLOATS;    // [16][GPL]  K-split partials / scratch (35 KB)

  const int tid = threadIdx.x;
  const int blk = blockIdx.x;
  const int pod = blk & (PODS - 1);
  const int gb  = blk >> 2;          // 0..63 within pod
  const int b0  = pod * BT;
  const int j0  = gb * JT;
  unsigned* fl  = flags + pod * FLAG_STRIDE;

  // GEMM mapping: thread = (ks 0..15 K-slice, gt 0..15 gate pair).
  const int ks = tid & 15;
  const int gt = tid >> 4;
  const int p  = ks & 7;

  // Update mapping (static across steps -> c stays in a register).
  const bool upd = tid < BT * JT;
  const int  ub  = tid >> 3, ujl = tid & 7;
  float c_reg = 0.f;

  float wA[34], wB[34], bA, bB;
  load_w(eWih, eWhh, ebih, ebhh, j0, ks, gt, p, wA, wB, bA, bB);

  #pragma unroll 1
  for (int phase = 0; phase < 2; ++phase) {
    #pragma unroll 1
    for (int step = 0; step < TT; ++step) {
      const int s = phase * TT + step;       // global step 0..1023
      const int t = phase ? (TT - 1 - step) : step;
      const int par = s & 1;
      const float* hrd = hbuf + par * (BB * HH);
      float*       hwr = hbuf + (par ^ 1) * (BB * HH);

      // ---- distributed-flag pod barrier: wait for all flags >= s ----
      if (tid < GBLK) {
        const unsigned* f = fl + tid;
        while (__hip_atomic_load(f, __ATOMIC_RELAXED, __HIP_MEMORY_SCOPE_AGENT)
               < (unsigned)s)
          __builtin_amdgcn_s_sleep(1);
      }
      __syncthreads();

      // ---- stage h (sc1 bypass loads, LLC-coherent) and x[:, t, :] ----
      #pragma unroll
      for (int rep = 0; rep < (BT * (HH / 2)) / NTHR; ++rep) {
        const int idx = rep * NTHR + tid;
        const int b = idx >> 8, k2 = idx & 255;
        const u64 v = __hip_atomic_load(
            (const u64*)(hrd + (b0 + b) * HH) + k2,
            __ATOMIC_RELAXED, __HIP_MEMORY_SCOPE_AGENT);
        float2 f2; __builtin_memcpy(&f2, &v, 8);
        *(float2*)&U[b * KP + (k2 << 1)] = f2;
      }
      if (tid < BT * (FF / 4)) {
        const int b = tid >> 3, k4 = (tid & 7) << 2;
        *(f4v*)&U[b * KP + HH + k4] = *(const f4v*)&x[((b0 + b) * TT + t) * FF + k4];
      }
      __syncthreads();

      // ---- GEMM: weights in regs, U from LDS (XOR-decollided b128 reads) ----
      float acc0[16], acc1[16];
      #pragma unroll
      for (int b = 0; b < 16; ++b) {
        acc0[b] = (ks == 0) ? bA : 0.f;
        acc1[b] = (ks == 0) ? bB : 0.f;
      }
      {
        const float* Uk = U + ks * 32;
        #pragma unroll
        for (int b = 0; b < 16; ++b) {
          const float* Ub = Uk + b * KP;
          #pragma unroll
          for (int kk = 0; kk < 8; ++kk) {
            const f4v u = *(const f4v*)(Ub + ((kk ^ p) << 2));
            #pragma unroll
            for (int c = 0; c < 4; ++c) {
              acc0[b] += u[c] * wA[kk * 4 + c];
              acc1[b] += u[c] * wB[kk * 4 + c];
            }
          }
          const float2 ux = *(const float2*)(U + b * KP + HH + ks * 2);
          acc0[b] += ux.x * wA[32] + ux.y * wA[33];
          acc1[b] += ux.x * wB[32] + ux.y * wB[33];
        }
      }
      {
        float* Gw = Gr + ks * GPL + gt;
        #pragma unroll
        for (int b = 0; b < 16; ++b) {
          Gw[b * GRS]      = acc0[b];
          Gw[b * GRS + 16] = acc1[b];
        }
      }
      __syncthreads();

      // ---- reduce K-split partials, activations, state update ----
      if (upd) {
        float si = 0.f, sf = 0.f, sg = 0.f, so = 0.f;
        const float* Grd = Gr + ub * GRS + ujl;
        #pragma unroll
        for (int q = 0; q < 16; ++q) {
          const float* g = Grd + q * GPL;
          si += g[0]; sf += g[8]; sg += g[16]; so += g[24];
        }
        const float c2 = sigmf(sf) * c_reg + sigmf(si) * tanhfast(sg);
        const float h2 = sigmf(so) * tanhfast(c2);
        c_reg = c2;
        __hip_atomic_store(&hwr[(b0 + ub) * HH + j0 + ujl], h2,
                           __ATOMIC_RELAXED, __HIP_MEMORY_SCOPE_AGENT);
        // Drain the write-through store so the flag can't pass it.
        asm volatile("s_waitcnt vmcnt(0)" ::: "memory");
      }
      __syncthreads();

      // ---- arrive: one store, no RMW ----
      if (tid == 0)
        __hip_atomic_store(fl + gb, (unsigned)(s + 1),
                           __ATOMIC_RELAXED, __HIP_MEMORY_SCOPE_AGENT);

      // ---- decoder out-projection (AFTER flag: hides under peers' poll).
      // Uses U = h(t) staged this step (pre-update), faithful to reference. ----
      if (phase && gb < FF) {
        const int f  = gb;
        const int ob = tid >> 4, seg = tid & 15;
        const float* wrow = Wo + f * HH + seg * 32;
        const float* urow = U + ob * KP + seg * 32;
        float pj = 0.f;
        #pragma unroll
        for (int k = 0; k < 32; k += 4) {
          const f4v wv = *(const f4v*)(wrow + k);
          const f4v uv = *(const f4v*)(urow + k);
          pj += uv[0] * wv[0] + uv[1] * wv[1] + uv[2] * wv[2] + uv[3] * wv[3];
        }
        Gr[tid] = pj;          // Gr free until next step's GEMM
        __syncthreads();
        if (tid < BT) {
          float sm = 0.f;
          #pragma unroll
          for (int q = 0; q < 16; ++q) sm += Gr[(tid << 4) + q];
          out[((b0 + tid) * TT + t) * FF + f] = sm + bo[f];
        }
      }
    }
    if (phase == 0)  // encoder done: swap register weights to decoder
      load_w(dWih, dWhh, dbih, dbhh, j0, ks, gt, p, wA, wB, bA, bB);
  }
}

extern "C" void kernel_launch(void* const* d_in, const int* in_sizes, int n_in,
                              void* d_out, int out_size, void* d_ws, size_t ws_size,
                              hipStream_t stream) {
  const float* x    = (const float*)d_in[0];
  const float* eWih = (const float*)d_in[1];   // enc_Wih0 [2048,32]
  const float* eWhh = (const float*)d_in[2];   // enc_Whh0 [2048,512]
  const float* ebih = (const float*)d_in[3];
  const float* ebhh = (const float*)d_in[4];
  // d_in[5..8] enc layer 1: dead (only feeds dead decoder layer 1)
  const float* dWih = (const float*)d_in[9];   // dec_Wih0
  const float* dWhh = (const float*)d_in[10];  // dec_Whh0
  const float* dbih = (const float*)d_in[11];
  const float* dbhh = (const float*)d_in[12];
  // d_in[13..16] dec layer 1: dead (hB/cB never reach outs)
  const float* Wo   = (const float*)d_in[17];  // [32,512]
  const float* bo   = (const float*)d_in[18];  // [32]
  float* out = (float*)d_out;

  float*    hbuf  = (float*)d_ws;              // [2][64][512] parity-buffered h
  unsigned* flags = (unsigned*)(hbuf + 2 * BB * HH);

  hipFuncSetAttribute(reinterpret_cast<const void*>(lstm_ae_kernel),
                      hipFuncAttributeMaxDynamicSharedMemorySize, LDS_BYTES);

  init_ws_kernel<<<dim3((2 * BB * HH + NTHR - 1) / NTHR), dim3(NTHR), 0, stream>>>(hbuf, flags);
  lstm_ae_kernel<<<dim3(NBLK), dim3(NTHR), LDS_BYTES, stream>>>(
      x, eWih, eWhh, ebih, ebhh, dWih, dWhh, dbih, dbhh, Wo, bo,
      out, hbuf, flags);
}

// Round 4
// 10180.054 us; speedup vs baseline: 1.0145x; 1.0145x over previous
//
#include <hip/hip_runtime.h>

// LSTMAutoEncoder: B=64, T=512, H=512, F=32.
// Dead-code analysis: only encoder layer 0 (final h,c) and decoder layer 0
// feed the output: out[:, t, :] = h_dec0_before_step(511-t) @ W_out^T + b_out.
// -> 1024 sequential LSTM cell steps; batch split into 8 independent pods of
// 8 rows x 32 blocks (256 blocks, 1/CU).
//
// Round 4 design (fixing round 3's bank-conflict regression):
//  - Thread map (ks = tid>>4, gt = tid&15): each wave carries only 4 distinct
//    K-slices -> every U ds_read_b128 has 4 unique addresses (16-lane
//    broadcast each); XOR visit order (kk^p) places them in 4 distinct bank
//    groups -> conflict-free, 4x less LDS data after dedup.
//  - Thread (ks,gt) owns gate rows {i,f,g,o} of hidden index j0+gt: one U
//    read feeds 16 FMAs.
//  - Weights in VGPRs (136 f32/thread); no weight LDS traffic in the K-loop.
//  - Distributed flag barrier, flags 64B apart (no shared-line hammering);
//    arrive-before-out-projection hides the projection under peers' poll.
//  - h exchange: sc1 write-through stores + sc1 bypass loads (LLC-coherent,
//    no L2-maintenance ops); parity double-buffer; c never leaves its reg.

#define BB   64
#define TT   512
#define HH   512
#define FF   32
#define KP   548              // U row stride (floats): 512 h + 32 x + pad
#define PODS 8
#define BT   8                // batch rows per pod
#define GBLK 32               // blocks per pod
#define JT   16               // hidden indices per block
#define NTHR 256
#define NBLK (PODS * GBLK)
#define GRS  66               // Gr batch-row stride (64 gates + 2 pad)
#define GPL  (BT * GRS + 2)   // 530: per-ks plane stride
#define U_FLOATS  (BT * KP)   // 4384
#define GR_FLOATS (16 * GPL)  // 8480
#define LDS_FLOATS (U_FLOATS + GR_FLOATS)
#define LDS_BYTES  (LDS_FLOATS * 4)
#define FLAG_SP  16           // u32 between flags (64 B)
#define FLAG_POD (GBLK * FLAG_SP)

typedef float f4v __attribute__((ext_vector_type(4)));
typedef unsigned long long u64;

__device__ __forceinline__ float sigmf(float x)    { return 1.f / (1.f + __expf(-x)); }
__device__ __forceinline__ float tanhfast(float x) { return 1.f - 2.f / (__expf(2.f * x) + 1.f); }

// Thread (ks, gt) owns gate rows m*HH + j0 + gt (m = i,f,g,o) and K-slice
// [ks*32, ks*32+32) of Whh + x-cols {2ks, 2ks+1} of Wih. Register index is
// STATIC (kk); the XOR visit-order permutation lives in the address only.
__device__ __forceinline__ void load_w(
    const float* __restrict__ Wih, const float* __restrict__ Whh,
    const float* __restrict__ bih, const float* __restrict__ bhh,
    int j0, int ks, int gt, int p, f4v wv[4][8], float2 wx[4], float bias[4])
{
  #pragma unroll
  for (int m = 0; m < 4; ++m) {
    const int g = m * HH + j0 + gt;
    #pragma unroll
    for (int kk = 0; kk < 8; ++kk) {
      const int q = ks * 32 + ((kk ^ p) << 2);
      wv[m][kk] = *(const f4v*)&Whh[g * HH + q];
    }
    wx[m]   = *(const float2*)&Wih[g * FF + ks * 2];
    bias[m] = bih[g] + bhh[g];
  }
}

__global__ void init_ws_kernel(float* hbuf, unsigned* flags) {
  const int i = blockIdx.x * blockDim.x + threadIdx.x;
  if (i < 2 * BB * HH) hbuf[i] = 0.f;
  if (i < PODS * FLAG_POD) flags[i] = 0u;
}

__global__ void __launch_bounds__(NTHR, 1)
lstm_ae_kernel(const float* __restrict__ x,
               const float* __restrict__ eWih, const float* __restrict__ eWhh,
               const float* __restrict__ ebih, const float* __restrict__ ebhh,
               const float* __restrict__ dWih, const float* __restrict__ dWhh,
               const float* __restrict__ dbih, const float* __restrict__ dbhh,
               const float* __restrict__ Wo,  const float* __restrict__ bo,
               float* __restrict__ out, float* __restrict__ hbuf,
               unsigned* __restrict__ flags)
{
  extern __shared__ float lds[];
  float* U  = lds;               // [BT][KP]   h | x_t
  float* Gr = lds + U_FLOATS;    // [16][GPL]  K-split partials / scratch

  const int tid = threadIdx.x;
  const int blk = blockIdx.x;
  const int pod = blk & (PODS - 1);  // round-robin -> pod sits on one XCD
  const int gb  = blk >> 3;          // 0..31 within pod
  const int b0  = pod * BT;
  const int j0  = gb * JT;
  unsigned* fl  = flags + pod * FLAG_POD;

  // GEMM mapping: 4 distinct ks per wave -> broadcast-heavy LDS reads.
  const int ks = tid >> 4;       // K-slice 0..15
  const int gt = tid & 15;       // hidden index within block
  const int p  = ks & 7;

  // Update mapping (static across steps -> c stays in a register).
  const bool upd = tid < BT * JT;            // 128 threads
  const int  ub  = tid >> 4, ujl = tid & 15;
  float c_reg = 0.f;

  f4v   wv[4][8];
  float2 wx[4];
  float bias[4];
  load_w(eWih, eWhh, ebih, ebhh, j0, ks, gt, p, wv, wx, bias);

  #pragma unroll 1
  for (int phase = 0; phase < 2; ++phase) {
    #pragma unroll 1
    for (int step = 0; step < TT; ++step) {
      const int s = phase * TT + step;       // global step 0..1023
      const int t = phase ? (TT - 1 - step) : step;
      const int par = s & 1;
      const float* hrd = hbuf + par * (BB * HH);
      float*       hwr = hbuf + (par ^ 1) * (BB * HH);

      // ---- distributed-flag pod barrier: wait for all 32 flags >= s ----
      if (tid < GBLK) {
        const unsigned* f = fl + tid * FLAG_SP;
        while (__hip_atomic_load(f, __ATOMIC_RELAXED, __HIP_MEMORY_SCOPE_AGENT)
               < (unsigned)s)
          __builtin_amdgcn_s_sleep(1);
      }
      __syncthreads();

      // ---- stage h (sc1 bypass loads, LLC-coherent) and x[:, t, :] ----
      #pragma unroll
      for (int rep = 0; rep < (BT * (HH / 2)) / NTHR; ++rep) {  // 8 reps
        const int idx = rep * NTHR + tid;
        const int b = idx >> 8, k2 = idx & 255;
        const u64 v = __hip_atomic_load(
            (const u64*)(hrd + (b0 + b) * HH) + k2,
            __ATOMIC_RELAXED, __HIP_MEMORY_SCOPE_AGENT);
        float2 f2; __builtin_memcpy(&f2, &v, 8);
        *(float2*)&U[b * KP + (k2 << 1)] = f2;
      }
      if (tid < BT * (FF / 4)) {
        const int b = tid >> 3, k4 = (tid & 7) << 2;
        *(f4v*)&U[b * KP + HH + k4] = *(const f4v*)&x[((b0 + b) * TT + t) * FF + k4];
      }
      __syncthreads();

      // ---- GEMM: weights in regs; U reads are 4-unique-address b128
      //      (16-lane broadcast, 4 distinct bank groups via XOR) ----
      float acc[4][8];
      #pragma unroll
      for (int m = 0; m < 4; ++m)
        #pragma unroll
        for (int b = 0; b < 8; ++b) acc[m][b] = (ks == 0) ? bias[m] : 0.f;

      #pragma unroll
      for (int b = 0; b < 8; ++b) {
        const float* Ub = U + b * KP + ks * 32;
        #pragma unroll
        for (int kk = 0; kk < 8; ++kk) {
          const f4v u = *(const f4v*)(Ub + ((kk ^ p) << 2));
          #pragma unroll
          for (int m = 0; m < 4; ++m) {
            acc[m][b] += u[0] * wv[m][kk][0] + u[1] * wv[m][kk][1]
                       + u[2] * wv[m][kk][2] + u[3] * wv[m][kk][3];
          }
        }
        const float2 ux = *(const float2*)(U + b * KP + HH + ks * 2);
        #pragma unroll
        for (int m = 0; m < 4; ++m)
          acc[m][b] += ux.x * wx[m].x + ux.y * wx[m].y;
      }
      {
        float* Gw = Gr + ks * GPL + gt;
        #pragma unroll
        for (int b = 0; b < 8; ++b)
          #pragma unroll
          for (int m = 0; m < 4; ++m)
            Gw[b * GRS + m * 16] = acc[m][b];
      }
      __syncthreads();

      // ---- reduce 16 K-split partials, activations, state update ----
      if (upd) {
        const float* g0 = Gr + ub * GRS + ujl;
        float si = 0.f, sf = 0.f, sg = 0.f, so = 0.f;
        #pragma unroll
        for (int q = 0; q < 16; ++q) {
          const float* g = g0 + q * GPL;
          si += g[0]; sf += g[16]; sg += g[32]; so += g[48];
        }
        const float c2 = sigmf(sf) * c_reg + sigmf(si) * tanhfast(sg);
        const float h2 = sigmf(so) * tanhfast(c2);
        c_reg = c2;
        __hip_atomic_store(&hwr[(b0 + ub) * HH + j0 + ujl], h2,
                           __ATOMIC_RELAXED, __HIP_MEMORY_SCOPE_AGENT);
        // Drain the write-through store so the flag can't pass it.
        asm volatile("s_waitcnt vmcnt(0)" ::: "memory");
      }
      __syncthreads();

      // ---- arrive: one store per block, own 64B-padded flag ----
      if (tid == 0)
        __hip_atomic_store(fl + gb * FLAG_SP, (unsigned)(s + 1),
                           __ATOMIC_RELAXED, __HIP_MEMORY_SCOPE_AGENT);

      // ---- decoder out-projection (AFTER flag: hides under peers' poll).
      // Uses U = h(t) staged this step (pre-update), faithful to reference.
      // GBLK == FF: every block owns one feature. ----
      if (phase) {
        const int f   = gb;
        const int ob  = tid >> 5, seg = tid & 31;   // 8 rows x 32 segments
        const float* wrow = Wo + f * HH + seg * 16;
        const float* urow = U + ob * KP + seg * 16;
        float pj = 0.f;
        #pragma unroll
        for (int k = 0; k < 16; k += 4) {
          const f4v wvv = *(const f4v*)(wrow + k);
          const f4v uvv = *(const f4v*)(urow + k);
          pj += uvv[0] * wvv[0] + uvv[1] * wvv[1] + uvv[2] * wvv[2] + uvv[3] * wvv[3];
        }
        Gr[tid] = pj;          // Gr free until next step's GEMM (2 syncs away)
        __syncthreads();
        if (tid < BT) {
          float sm = 0.f;
          #pragma unroll
          for (int q = 0; q < 32; ++q) sm += Gr[(tid << 5) + q];
          out[((b0 + tid) * TT + t) * FF + f] = sm + bo[f];
        }
      }
    }
    if (phase == 0)  // encoder done: swap register weights to decoder
      load_w(dWih, dWhh, dbih, dbhh, j0, ks, gt, p, wv, wx, bias);
  }
}

extern "C" void kernel_launch(void* const* d_in, const int* in_sizes, int n_in,
                              void* d_out, int out_size, void* d_ws, size_t ws_size,
                              hipStream_t stream) {
  const float* x    = (const float*)d_in[0];
  const float* eWih = (const float*)d_in[1];   // enc_Wih0 [2048,32]
  const float* eWhh = (const float*)d_in[2];   // enc_Whh0 [2048,512]
  const float* ebih = (const float*)d_in[3];
  const float* ebhh = (const float*)d_in[4];
  // d_in[5..8] enc layer 1: dead (only feeds dead decoder layer 1)
  const float* dWih = (const float*)d_in[9];   // dec_Wih0
  const float* dWhh = (const float*)d_in[10];  // dec_Whh0
  const float* dbih = (const float*)d_in[11];
  const float* dbhh = (const float*)d_in[12];
  // d_in[13..16] dec layer 1: dead (hB/cB never reach outs)
  const float* Wo   = (const float*)d_in[17];  // [32,512]
  const float* bo   = (const float*)d_in[18];  // [32]
  float* out = (float*)d_out;

  float*    hbuf  = (float*)d_ws;              // [2][64][512] parity-buffered h
  unsigned* flags = (unsigned*)(hbuf + 2 * BB * HH);

  hipFuncSetAttribute(reinterpret_cast<const void*>(lstm_ae_kernel),
                      hipFuncAttributeMaxDynamicSharedMemorySize, LDS_BYTES);

  init_ws_kernel<<<dim3((2 * BB * HH + NTHR - 1) / NTHR), dim3(NTHR), 0, stream>>>(hbuf, flags);
  lstm_ae_kernel<<<dim3(NBLK), dim3(NTHR), LDS_BYTES, stream>>>(
      x, eWih, eWhh, ebih, ebhh, dWih, dWhh, dbih, dbhh, Wo, bo,
      out, hbuf, flags);
}

// Round 6
// 9181.300 us; speedup vs baseline: 1.1248x; 1.1088x over previous
//
#include <hip/hip_runtime.h>

// LSTMAutoEncoder: B=64, T=512, H=512, F=32.
// Dead-code analysis: only encoder layer 0 (final h,c) and decoder layer 0
// feed the output: out[:, t, :] = h_dec0_before_step(511-t) @ W_out^T + b_out.
// -> 1024 sequential LSTM cell steps; batch split into 8 independent pods of
// 8 rows x 32 blocks (256 blocks, 1/CU).
//
// Round 6: single-trip tagged-value exchange. Every h element is published as
// ONE 8-byte AGENT-scope atomic store {f32 h | u32 tag=s+1} -> no vmcnt drain,
// no separate flag, no separate poll. Consumers gather 16 tagged u64 each
// (pipelined), selectively re-load stale ones until tag >= s, scatter to LDS.
// Safety: parity double-buffer induction (as round 4) -> a producer cannot
// overwrite parity slot s&1 before all consumers of step s published s+1, so
// every spin terminates. Only proven primitives (rounds 2-4's u64 AGENT ops).

#define BB   64
#define TT   512
#define HH   512
#define FF   32
#define KP   548              // U row stride (floats): 512 h + 32 x + pad
#define PODS 8
#define BT   8                // batch rows per pod
#define GBLK 32               // blocks per pod
#define JT   16               // hidden indices per block
#define NTHR 256
#define NBLK (PODS * GBLK)
#define GRS  66               // Gr batch-row stride (64 gates + 2 pad)
#define GPL  (BT * GRS + 2)   // 530: per-ks plane stride
#define U_FLOATS  (BT * KP)   // 4384
#define GR_FLOATS (16 * GPL)  // 8480
#define LDS_FLOATS (U_FLOATS + GR_FLOATS)
#define LDS_BYTES  (LDS_FLOATS * 4)
#define PUB_U64  (2 * PODS * BT * HH)   // 65536 (512 KB in d_ws)

typedef float f4v __attribute__((ext_vector_type(4)));
typedef unsigned long long u64;

__device__ __forceinline__ float sigmf(float x)    { return 1.f / (1.f + __expf(-x)); }
__device__ __forceinline__ float tanhfast(float x) { return 1.f - 2.f / (__expf(2.f * x) + 1.f); }

// Thread (ks, gt) owns gate rows m*HH + j0 + gt (m = i,f,g,o) and K-slice
// [ks*32, ks*32+32) of Whh + x-cols {2ks, 2ks+1} of Wih. Register index is
// STATIC (kk); the XOR visit-order permutation lives in the address only.
__device__ __forceinline__ void load_w(
    const float* __restrict__ Wih, const float* __restrict__ Whh,
    const float* __restrict__ bih, const float* __restrict__ bhh,
    int j0, int ks, int gt, int p, f4v wv[4][8], float2 wx[4], float bias[4])
{
  #pragma unroll
  for (int m = 0; m < 4; ++m) {
    const int g = m * HH + j0 + gt;
    #pragma unroll
    for (int kk = 0; kk < 8; ++kk) {
      const int q = ks * 32 + ((kk ^ p) << 2);
      wv[m][kk] = *(const f4v*)&Whh[g * HH + q];
    }
    wx[m]   = *(const float2*)&Wih[g * FF + ks * 2];
    bias[m] = bih[g] + bhh[g];
  }
}

__global__ void init_ws_kernel(u64* pub) {
  const int i = blockIdx.x * blockDim.x + threadIdx.x;
  if (i < PUB_U64) pub[i] = 0ull;   // h = 0.0f, tag = 0 (both parities)
}

__global__ void __launch_bounds__(NTHR, 1)
lstm_ae_kernel(const float* __restrict__ x,
               const float* __restrict__ eWih, const float* __restrict__ eWhh,
               const float* __restrict__ ebih, const float* __restrict__ ebhh,
               const float* __restrict__ dWih, const float* __restrict__ dWhh,
               const float* __restrict__ dbih, const float* __restrict__ dbhh,
               const float* __restrict__ Wo,  const float* __restrict__ bo,
               float* __restrict__ out, u64* __restrict__ pub)
{
  extern __shared__ float lds[];
  float* U  = lds;               // [BT][KP]   h | x_t
  float* Gr = lds + U_FLOATS;    // [16][GPL]  K-split partials / scratch

  const int tid = threadIdx.x;
  const int blk = blockIdx.x;
  const int pod = blk & (PODS - 1);
  const int gb  = blk >> 3;          // 0..31 within pod
  const int b0  = pod * BT;
  const int j0  = gb * JT;

  // GEMM mapping: 4 distinct ks per wave -> broadcast-heavy LDS reads.
  const int ks = tid >> 4;       // K-slice 0..15
  const int gt = tid & 15;       // hidden index within block
  const int p  = ks & 7;

  // Update mapping (static across steps -> c stays in a register).
  const bool upd = tid < BT * JT;            // 128 threads
  const int  ub  = tid >> 4, ujl = tid & 15;
  float c_reg = 0.f;

  f4v   wv[4][8];
  float2 wx[4];
  float bias[4];
  load_w(eWih, eWhh, ebih, ebhh, j0, ks, gt, p, wv, wx, bias);

  #pragma unroll 1
  for (int phase = 0; phase < 2; ++phase) {
    #pragma unroll 1
    for (int step = 0; step < TT; ++step) {
      const int s = phase * TT + step;       // global step 0..1023
      const int t = phase ? (TT - 1 - step) : step;
      // pub layout: [par][pod][bl][j]; linear index = (par*PODS+pod)*BT*HH + bl*HH + j
      const u64* prd = pub + (size_t)((s & 1) * PODS + pod) * (BT * HH);
      u64*       pwr = pub + (size_t)(((s + 1) & 1) * PODS + pod) * (BT * HH);

      // ---- stage x[:, t, :] first (independent cached loads, overlap spin) ----
      if (tid < BT * (FF / 4)) {
        const int b = tid >> 3, k4 = (tid & 7) << 2;
        *(f4v*)&U[b * KP + HH + k4] = *(const f4v*)&x[((b0 + b) * TT + t) * FF + k4];
      }

      // ---- gather tagged h: 16 u64/thread, selective re-load of stale ----
      // element e = r*256 + tid -> bl = e>>9 = r>>1, j = e&511 = (r&1)*256+tid
      {
        const u64* gp = prd + tid;
        u64 v[16];
        unsigned rem = 0xFFFFu;
        while (rem) {
          #pragma unroll
          for (int r = 0; r < 16; ++r)
            if (rem & (1u << r))
              v[r] = __hip_atomic_load(gp + r * 256,
                                       __ATOMIC_RELAXED, __HIP_MEMORY_SCOPE_AGENT);
          #pragma unroll
          for (int r = 0; r < 16; ++r)
            if ((rem & (1u << r)) && (unsigned)(v[r] >> 32) >= (unsigned)s)
              rem &= ~(1u << r);
        }
        #pragma unroll
        for (int r = 0; r < 16; ++r)
          U[(r >> 1) * KP + (r & 1) * 256 + tid] = __uint_as_float((unsigned)v[r]);
      }
      __syncthreads();

      // ---- GEMM: weights in regs; U reads are 4-unique-address b128
      //      (16-lane broadcast, 4 distinct bank groups via XOR) ----
      float acc[4][8];
      #pragma unroll
      for (int m = 0; m < 4; ++m)
        #pragma unroll
        for (int b = 0; b < 8; ++b) acc[m][b] = (ks == 0) ? bias[m] : 0.f;

      #pragma unroll
      for (int b = 0; b < 8; ++b) {
        const float* Ub = U + b * KP + ks * 32;
        #pragma unroll
        for (int kk = 0; kk < 8; ++kk) {
          const f4v u = *(const f4v*)(Ub + ((kk ^ p) << 2));
          #pragma unroll
          for (int m = 0; m < 4; ++m) {
            acc[m][b] += u[0] * wv[m][kk][0] + u[1] * wv[m][kk][1]
                       + u[2] * wv[m][kk][2] + u[3] * wv[m][kk][3];
          }
        }
        const float2 ux = *(const float2*)(U + b * KP + HH + ks * 2);
        #pragma unroll
        for (int m = 0; m < 4; ++m)
          acc[m][b] += ux.x * wx[m].x + ux.y * wx[m].y;
      }
      {
        float* Gw = Gr + ks * GPL + gt;
        #pragma unroll
        for (int b = 0; b < 8; ++b)
          #pragma unroll
          for (int m = 0; m < 4; ++m)
            Gw[b * GRS + m * 16] = acc[m][b];
      }
      __syncthreads();

      // ---- reduce 16 K-split partials, activations, state update,
      //      single-trip tagged publish (no drain, no flag) ----
      if (upd) {
        const float* g0 = Gr + ub * GRS + ujl;
        float si = 0.f, sf = 0.f, sg = 0.f, so = 0.f;
        #pragma unroll
        for (int q = 0; q < 16; ++q) {
          const float* g = g0 + q * GPL;
          si += g[0]; sf += g[16]; sg += g[32]; so += g[48];
        }
        const float c2 = sigmf(sf) * c_reg + sigmf(si) * tanhfast(sg);
        const float h2 = sigmf(so) * tanhfast(c2);
        c_reg = c2;
        const u64 pk = ((u64)(unsigned)(s + 1) << 32) | (u64)__float_as_uint(h2);
        __hip_atomic_store(&pwr[ub * HH + j0 + ujl], pk,
                           __ATOMIC_RELAXED, __HIP_MEMORY_SCOPE_AGENT);
      }
      __syncthreads();   // protects Gr (reduce reads) from out-proj's Gr writes

      // ---- decoder out-projection (hides under peers' gather-spin).
      // Uses U = h(t) staged this step (pre-update), faithful to reference.
      // GBLK == FF: every block owns one feature. ----
      if (phase) {
        const int f   = gb;
        const int ob  = tid >> 5, seg = tid & 31;   // 8 rows x 32 segments
        const float* wrow = Wo + f * HH + seg * 16;
        const float* urow = U + ob * KP + seg * 16;
        float pj = 0.f;
        #pragma unroll
        for (int k = 0; k < 16; k += 4) {
          const f4v wvv = *(const f4v*)(wrow + k);
          const f4v uvv = *(const f4v*)(urow + k);
          pj += uvv[0] * wvv[0] + uvv[1] * wvv[1] + uvv[2] * wvv[2] + uvv[3] * wvv[3];
        }
        Gr[tid] = pj;          // Gr free until next step's GEMM
        __syncthreads();       // also orders U reads before next-iter gather
        if (tid < BT) {
          float sm = 0.f;
          #pragma unroll
          for (int q = 0; q < 32; ++q) sm += Gr[(tid << 5) + q];
          out[((b0 + tid) * TT + t) * FF + f] = sm + bo[f];
        }
      }
    }
    if (phase == 0)  // encoder done: swap register weights to decoder
      load_w(dWih, dWhh, dbih, dbhh, j0, ks, gt, p, wv, wx, bias);
  }
}

extern "C" void kernel_launch(void* const* d_in, const int* in_sizes, int n_in,
                              void* d_out, int out_size, void* d_ws, size_t ws_size,
                              hipStream_t stream) {
  const float* x    = (const float*)d_in[0];
  const float* eWih = (const float*)d_in[1];   // enc_Wih0 [2048,32]
  const float* eWhh = (const float*)d_in[2];   // enc_Whh0 [2048,512]
  const float* ebih = (const float*)d_in[3];
  const float* ebhh = (const float*)d_in[4];
  // d_in[5..8] enc layer 1: dead (only feeds dead decoder layer 1)
  const float* dWih = (const float*)d_in[9];   // dec_Wih0
  const float* dWhh = (const float*)d_in[10];  // dec_Whh0
  const float* dbih = (const float*)d_in[11];
  const float* dbhh = (const float*)d_in[12];
  // d_in[13..16] dec layer 1: dead (hB/cB never reach outs)
  const float* Wo   = (const float*)d_in[17];  // [32,512]
  const float* bo   = (const float*)d_in[18];  // [32]
  float* out = (float*)d_out;

  u64* pubbuf = (u64*)d_ws;                    // [2][PODS][BT][HH] tagged h

  hipFuncSetAttribute(reinterpret_cast<const void*>(lstm_ae_kernel),
                      hipFuncAttributeMaxDynamicSharedMemorySize, LDS_BYTES);

  init_ws_kernel<<<dim3((PUB_U64 + NTHR - 1) / NTHR), dim3(NTHR), 0, stream>>>(pubbuf);
  lstm_ae_kernel<<<dim3(NBLK), dim3(NTHR), LDS_BYTES, stream>>>(
      x, eWih, eWhh, ebih, ebhh, dWih, dWhh, dbih, dbhh, Wo, bo,
      out, pubbuf);
}

// Round 7
// 9025.420 us; speedup vs baseline: 1.1443x; 1.0173x over previous
//
#include <hip/hip_runtime.h>

// LSTMAutoEncoder: B=64, T=512, H=512, F=32.
// Dead-code analysis: only encoder layer 0 (final h,c) and decoder layer 0
// feed the output: out[:, t, :] = h_dec0_before_step(511-t) @ W_out^T + b_out.
// -> 1024 sequential LSTM cell steps; batch split into 8 independent pods of
// 8 rows x 32 blocks (256 blocks, 1/CU).
//
// Round 7: wave-decoupled dataflow. Wave w consumes ONLY h cols [128w,128w+128)
// (its GEMM K-slices) -> per-wave gather of 1024 tagged u64 (8 producer blocks)
// with s_sleep backoff, private U/Gr segments, NO barrier between gather and
// GEMM. Decoder out-projection computed as per-wave column partials during the
// GEMM phase and reduced by idle wave-3 threads during the update phase ->
// exactly 2 __syncthreads per step in both phases.
// Exchange primitive unchanged from r6: one 8-byte AGENT-scope atomic store
// {f32 h | u32 tag=s+1} per element; parity double-buffer induction.

#define BB   64
#define TT   512
#define HH   512
#define FF   32
#define KP   548              // U row stride (floats): 512 h + 32 x + pad
#define PODS 8
#define BT   8                // batch rows per pod
#define GBLK 32               // blocks per pod
#define JT   16               // hidden indices per block
#define NTHR 256
#define NBLK (PODS * GBLK)
#define GRS  66               // Gr batch-row stride (64 gates + 2 pad)
#define GPL  (BT * GRS + 2)   // 530: per-ks plane stride
#define U_FLOATS  (BT * KP)   // 4384
#define GR_FLOATS (16 * GPL)  // 8480
#define OPW_FLOATS 256        // [4 waves][64 lanes] out-projection partials
#define LDS_FLOATS (U_FLOATS + GR_FLOATS + OPW_FLOATS)
#define LDS_BYTES  (LDS_FLOATS * 4)
#define PUB_U64  (2 * PODS * BT * HH)   // 65536 (512 KB in d_ws)

typedef float f4v __attribute__((ext_vector_type(4)));
typedef unsigned long long u64;

__device__ __forceinline__ float sigmf(float x)    { return 1.f / (1.f + __expf(-x)); }
__device__ __forceinline__ float tanhfast(float x) { return 1.f - 2.f / (__expf(2.f * x) + 1.f); }

// Thread (ks, gt) owns gate rows m*HH + j0 + gt (m = i,f,g,o) and K-slice
// [ks*32, ks*32+32) of Whh + x-cols {2ks, 2ks+1} of Wih. Register index is
// STATIC (kk); the XOR visit-order permutation lives in the address only.
__device__ __forceinline__ void load_w(
    const float* __restrict__ Wih, const float* __restrict__ Whh,
    const float* __restrict__ bih, const float* __restrict__ bhh,
    int j0, int ks, int gt, int p, f4v wv[4][8], float2 wx[4], float bias[4])
{
  #pragma unroll
  for (int m = 0; m < 4; ++m) {
    const int g = m * HH + j0 + gt;
    #pragma unroll
    for (int kk = 0; kk < 8; ++kk) {
      const int q = ks * 32 + ((kk ^ p) << 2);
      wv[m][kk] = *(const f4v*)&Whh[g * HH + q];
    }
    wx[m]   = *(const float2*)&Wih[g * FF + ks * 2];
    bias[m] = bih[g] + bhh[g];
  }
}

__global__ void init_ws_kernel(u64* pub) {
  const int i = blockIdx.x * blockDim.x + threadIdx.x;
  if (i < PUB_U64) pub[i] = 0ull;   // h = 0.0f, tag = 0 (both parities)
}

__global__ void __launch_bounds__(NTHR, 1)
lstm_ae_kernel(const float* __restrict__ x,
               const float* __restrict__ eWih, const float* __restrict__ eWhh,
               const float* __restrict__ ebih, const float* __restrict__ ebhh,
               const float* __restrict__ dWih, const float* __restrict__ dWhh,
               const float* __restrict__ dbih, const float* __restrict__ dbhh,
               const float* __restrict__ Wo,  const float* __restrict__ bo,
               float* __restrict__ out, u64* __restrict__ pub)
{
  extern __shared__ float lds[];
  float* U   = lds;                          // [BT][KP]   h | x_t
  float* Gr  = lds + U_FLOATS;               // [16][GPL]  K-split partials
  float* OPW = lds + U_FLOATS + GR_FLOATS;   // [4][64]    out-proj partials

  const int tid = threadIdx.x;
  const int blk = blockIdx.x;
  const int pod = blk & (PODS - 1);
  const int gb  = blk >> 3;          // 0..31 within pod
  const int b0  = pod * BT;
  const int j0  = gb * JT;

  // Wave-local gather mapping: wave w owns h cols [128w, 128w+128).
  const int w    = tid >> 6;         // wave 0..3
  const int lane = tid & 63;
  const int gl_b = lane >> 3;        // batch row 0..7
  const int gl_c = lane & 7;         // col sub-offset
  const int c0   = w * 128 + gl_c;   // gathered cols: c0 + 8r, r=0..15

  // GEMM mapping: 4 distinct ks per wave -> broadcast-heavy LDS reads,
  // all of wave w's reads fall in its own gathered U columns.
  const int ks = tid >> 4;           // K-slice 0..15 (wave w: 4w..4w+3)
  const int gt = tid & 15;           // hidden index within block
  const int p  = ks & 7;

  // Update mapping (static across steps -> c stays in a register).
  const bool upd = tid < BT * JT;            // waves 0-1
  const int  ub  = tid >> 4, ujl = tid & 15;
  float c_reg = 0.f;

  f4v   wv[4][8];
  float2 wx[4];
  float bias[4];
  load_w(eWih, eWhh, ebih, ebhh, j0, ks, gt, p, wv, wx, bias);

  #pragma unroll 1
  for (int phase = 0; phase < 2; ++phase) {
    #pragma unroll 1
    for (int step = 0; step < TT; ++step) {
      const int s = phase * TT + step;       // global step 0..1023
      const int t = phase ? (TT - 1 - step) : step;
      // pub layout: [par][pod][bl][j]
      const u64* prd = pub + (size_t)((s & 1) * PODS + pod) * (BT * HH);
      u64*       pwr = pub + (size_t)(((s + 1) & 1) * PODS + pod) * (BT * HH);

      // ---- per-wave gather (1024 tagged u64, 16/lane, coalesced 64B runs)
      //      with s_sleep backoff; then stage own U segment + own x slice ----
      {
        const u64* gp = prd + gl_b * HH + c0;
        u64 v[16];
        unsigned rem = 0xFFFFu;
        while (rem) {
          #pragma unroll
          for (int r = 0; r < 16; ++r)
            if (rem & (1u << r))
              v[r] = __hip_atomic_load(gp + 8 * r,
                                       __ATOMIC_RELAXED, __HIP_MEMORY_SCOPE_AGENT);
          #pragma unroll
          for (int r = 0; r < 16; ++r)
            if ((rem & (1u << r)) && (unsigned)(v[r] >> 32) >= (unsigned)s)
              rem &= ~(1u << r);
          if (rem) __builtin_amdgcn_s_sleep(1);   // backoff: no MALL hammering
        }
        #pragma unroll
        for (int r = 0; r < 16; ++r)
          U[gl_b * KP + c0 + 8 * r] = __uint_as_float((unsigned)v[r]);
        // x slice for this wave's K-range (cols 8w..8w+8), all 8 rows.
        U[gl_b * KP + HH + w * 8 + gl_c] =
            x[((b0 + gl_b) * TT + t) * FF + w * 8 + gl_c];
      }
      // NO barrier: U cols + Gr planes are wave-private until the reduce.

      // ---- GEMM: weights in regs; U reads are 4-unique-address b128
      //      (16-lane broadcast, 4 distinct bank groups via XOR) ----
      float acc[4][8];
      #pragma unroll
      for (int m = 0; m < 4; ++m)
        #pragma unroll
        for (int b = 0; b < 8; ++b) acc[m][b] = (ks == 0) ? bias[m] : 0.f;

      #pragma unroll
      for (int b = 0; b < 8; ++b) {
        const float* Ub = U + b * KP + ks * 32;
        #pragma unroll
        for (int kk = 0; kk < 8; ++kk) {
          const f4v u = *(const f4v*)(Ub + ((kk ^ p) << 2));
          #pragma unroll
          for (int m = 0; m < 4; ++m) {
            acc[m][b] += u[0] * wv[m][kk][0] + u[1] * wv[m][kk][1]
                       + u[2] * wv[m][kk][2] + u[3] * wv[m][kk][3];
          }
        }
        const float2 ux = *(const float2*)(U + b * KP + HH + ks * 2);
        #pragma unroll
        for (int m = 0; m < 4; ++m)
          acc[m][b] += ux.x * wx[m].x + ux.y * wx[m].y;
      }
      {
        float* Gw = Gr + ks * GPL + gt;
        #pragma unroll
        for (int b = 0; b < 8; ++b)
          #pragma unroll
          for (int m = 0; m < 4; ++m)
            Gw[b * GRS + m * 16] = acc[m][b];
      }

      // ---- decoder out-projection partials (wave-private U columns).
      // out[:, t, gb] uses h(t) BEFORE the update — exactly this step's U. ----
      if (phase) {
        const float* wrow = Wo + gb * HH + w * 128 + gl_c * 16;
        const float* urow = U + gl_b * KP + w * 128 + gl_c * 16;
        float pj = 0.f;
        #pragma unroll
        for (int k = 0; k < 16; k += 4) {
          const f4v wvv = *(const f4v*)(wrow + k);
          const f4v uvv = *(const f4v*)(urow + k);
          pj += uvv[0] * wvv[0] + uvv[1] * wvv[1] + uvv[2] * wvv[2] + uvv[3] * wvv[3];
        }
        OPW[w * 64 + lane] = pj;
      }
      __syncthreads();   // BAR A: Gr/OPW complete

      // ---- reduce 16 K-split partials, activations, state update,
      //      single-trip tagged publish (waves 0-1) ----
      if (upd) {
        const float* g0 = Gr + ub * GRS + ujl;
        float si = 0.f, sf = 0.f, sg = 0.f, so = 0.f;
        #pragma unroll
        for (int q = 0; q < 16; ++q) {
          const float* g = g0 + q * GPL;
          si += g[0]; sf += g[16]; sg += g[32]; so += g[48];
        }
        const float c2 = sigmf(sf) * c_reg + sigmf(si) * tanhfast(sg);
        const float h2 = sigmf(so) * tanhfast(c2);
        c_reg = c2;
        const u64 pk = ((u64)(unsigned)(s + 1) << 32) | (u64)__float_as_uint(h2);
        __hip_atomic_store(&pwr[ub * HH + j0 + ujl], pk,
                           __ATOMIC_RELAXED, __HIP_MEMORY_SCOPE_AGENT);
      }
      // ---- out-projection reduce by 8 idle wave-3 threads ----
      if (phase && tid >= 192 && tid < 200) {
        const int b = tid - 192;
        float sm = 0.f;
        #pragma unroll
        for (int w2 = 0; w2 < 4; ++w2)
          #pragma unroll
          for (int k = 0; k < 8; ++k)
            sm += OPW[w2 * 64 + b * 8 + k];
        out[((b0 + b) * TT + t) * FF + gb] = sm + bo[gb];
      }
      __syncthreads();   // BAR B: Gr/OPW free for next step
    }
    if (phase == 0)  // encoder done: swap register weights to decoder
      load_w(dWih, dWhh, dbih, dbhh, j0, ks, gt, p, wv, wx, bias);
  }
}

extern "C" void kernel_launch(void* const* d_in, const int* in_sizes, int n_in,
                              void* d_out, int out_size, void* d_ws, size_t ws_size,
                              hipStream_t stream) {
  const float* x    = (const float*)d_in[0];
  const float* eWih = (const float*)d_in[1];   // enc_Wih0 [2048,32]
  const float* eWhh = (const float*)d_in[2];   // enc_Whh0 [2048,512]
  const float* ebih = (const float*)d_in[3];
  const float* ebhh = (const float*)d_in[4];
  // d_in[5..8] enc layer 1: dead (only feeds dead decoder layer 1)
  const float* dWih = (const float*)d_in[9];   // dec_Wih0
  const float* dWhh = (const float*)d_in[10];  // dec_Whh0
  const float* dbih = (const float*)d_in[11];
  const float* dbhh = (const float*)d_in[12];
  // d_in[13..16] dec layer 1: dead (hB/cB never reach outs)
  const float* Wo   = (const float*)d_in[17];  // [32,512]
  const float* bo   = (const float*)d_in[18];  // [32]
  float* out = (float*)d_out;

  u64* pubbuf = (u64*)d_ws;                    // [2][PODS][BT][HH] tagged h

  hipFuncSetAttribute(reinterpret_cast<const void*>(lstm_ae_kernel),
                      hipFuncAttributeMaxDynamicSharedMemorySize, LDS_BYTES);

  init_ws_kernel<<<dim3((PUB_U64 + NTHR - 1) / NTHR), dim3(NTHR), 0, stream>>>(pubbuf);
  lstm_ae_kernel<<<dim3(NBLK), dim3(NTHR), LDS_BYTES, stream>>>(
      x, eWih, eWhh, ebih, ebhh, dWih, dWhh, dbih, dbhh, Wo, bo,
      out, pubbuf);
}

// Round 8
// 6112.786 us; speedup vs baseline: 1.6895x; 1.4765x over previous
//
#include <hip/hip_runtime.h>

// LSTMAutoEncoder: B=64, T=512, H=512, F=32.
// Dead-code: only encoder L0 (final h,c) and decoder L0 feed the output:
//   out[:, t, :] = h_dec0_before_step(511-t) @ W_out^T + b_out
// -> 1024 sequential cell steps; batch in 8 independent pods of 8 rows x 32
// blocks (256 blocks, 1/CU).
//
// Round 8: chunked gather-compute pipeline. Wave w's 128 h-cols = 8 chunks of
// 16 (one per producer). Weights are chunk-major (every thread owns 4 cols of
// every chunk) so each arriving chunk feeds 128 FMA/lane immediately; tag
// loads prefetch 4 chunks ahead (static unroll). x staged before the spin.
// ONE barrier/step: Gr + OPW parity double-buffered, U is wave-private.
// Exchange primitive unchanged: one 8-byte AGENT-scope atomic {f32 h|u32 tag}.

#define BB   64
#define TT   512
#define HH   512
#define FF   32
#define KP   548              // U row stride (floats): 512 h + 32 x + pad
#define PODS 8
#define BT   8                // batch rows per pod
#define GBLK 32               // blocks per pod
#define JT   16               // hidden indices per block
#define NTHR 256
#define NBLK (PODS * GBLK)
#define GRS  66               // Gr batch-row stride (64 gates + 2 pad)
#define GPL  (BT * GRS + 2)   // 530: per-ks plane stride
#define GRF  (16 * GPL)       // 8480 floats per parity
#define U_FLOATS  (BT * KP)   // 4384
#define OPWF 256              // [4][64] out-proj partials per parity
#define LDS_FLOATS (U_FLOATS + 2 * GRF + 2 * OPWF)   // 21856 (87.4 KB)
#define LDS_BYTES  (LDS_FLOATS * 4)
#define PUB_U64  (2 * PODS * BT * HH)   // 65536 (512 KB in d_ws)

typedef float f4v __attribute__((ext_vector_type(4)));
typedef unsigned long long u64;

__device__ __forceinline__ float sigmf(float x)    { return 1.f / (1.f + __expf(-x)); }
__device__ __forceinline__ float tanhfast(float x) { return 1.f - 2.f / (__expf(2.f * x) + 1.f); }

// Thread (w, kap, gt) owns, for every chunk q=0..7, cols [128w+16q+4kap, +4)
// of the 4 gate rows {m*HH + j0 + gt} plus x-cols {8w+2kap, +1}.
__device__ __forceinline__ void load_w(
    const float* __restrict__ Wih, const float* __restrict__ Whh,
    const float* __restrict__ bih, const float* __restrict__ bhh,
    int j0, int w, int kap, int gt, f4v wv[4][8], float2 wx[4], float bias[4])
{
  #pragma unroll
  for (int m = 0; m < 4; ++m) {
    const int g = m * HH + j0 + gt;
    #pragma unroll
    for (int q = 0; q < 8; ++q)
      wv[m][q] = *(const f4v*)&Whh[g * HH + w * 128 + q * 16 + kap * 4];
    wx[m]   = *(const float2*)&Wih[g * FF + w * 8 + kap * 2];
    bias[m] = bih[g] + bhh[g];
  }
}

__global__ void init_ws_kernel(u64* pub) {
  const int i = blockIdx.x * blockDim.x + threadIdx.x;
  if (i < PUB_U64) pub[i] = 0ull;   // h = 0.0f, tag = 0 (both parities)
}

__global__ void __launch_bounds__(NTHR, 1)
lstm_ae_kernel(const float* __restrict__ x,
               const float* __restrict__ eWih, const float* __restrict__ eWhh,
               const float* __restrict__ ebih, const float* __restrict__ ebhh,
               const float* __restrict__ dWih, const float* __restrict__ dWhh,
               const float* __restrict__ dbih, const float* __restrict__ dbhh,
               const float* __restrict__ Wo,  const float* __restrict__ bo,
               float* __restrict__ out, u64* __restrict__ pub)
{
  extern __shared__ float lds[];
  float* U   = lds;                      // [BT][KP]      h | x_t (wave-private cols)
  float* Gr  = lds + U_FLOATS;           // [2][16][GPL]  K-split partials (parity)
  float* OPW = lds + U_FLOATS + 2 * GRF; // [2][4][64]    out-proj partials (parity)

  const int tid = threadIdx.x;
  const int blk = blockIdx.x;
  const int pod = blk & (PODS - 1);
  const int gb  = blk >> 3;          // 0..31 within pod
  const int b0  = pod * BT;
  const int j0  = gb * JT;

  const int w    = tid >> 6;         // wave 0..3: owns h cols [128w,128w+128)
  const int lane = tid & 63;
  const int row  = lane >> 3;        // batch row 0..7
  const int sub  = lane & 7;         // col sub-offset within chunk
  const int cbase = w * 128 + sub;   // gather cols: cbase+16q, cbase+16q+8

  const int ks  = tid >> 4;          // K-slice id 0..15 (for Gr plane index)
  const int kap = ks & 3;            // chunk-column group 0..3
  const int gt  = tid & 15;          // hidden index within block

  // Update mapping (static across steps -> c stays in a register).
  const bool upd = tid < BT * JT;            // waves 0-1
  const int  ub  = tid >> 4, ujl = tid & 15;
  float c_reg = 0.f;

  f4v   wv[4][8];
  float2 wx[4];
  float bias[4];
  load_w(eWih, eWhh, ebih, ebhh, j0, w, kap, gt, wv, wx, bias);

  #pragma unroll 1
  for (int phase = 0; phase < 2; ++phase) {
    #pragma unroll 1
    for (int step = 0; step < TT; ++step) {
      const int s = phase * TT + step;       // global step 0..1023
      const int t = phase ? (TT - 1 - step) : step;
      const u64* prd = pub + (size_t)((s & 1) * PODS + pod) * (BT * HH);
      u64*       pwr = pub + (size_t)(((s + 1) & 1) * PODS + pod) * (BT * HH);
      float* Grp = Gr + (s & 1) * GRF;
      float* OPp = OPW + (s & 1) * OPWF;

      // ---- stage this wave's x slice first (latency overlaps the spin) ----
      U[row * KP + HH + w * 8 + sub] = x[((b0 + row) * TT + t) * FF + w * 8 + sub];

      // ---- chunked gather + GEMM, prefetch depth 4 ----
      float acc[4][8];
      #pragma unroll
      for (int m = 0; m < 4; ++m)
        #pragma unroll
        for (int b = 0; b < 8; ++b) acc[m][b] = (ks == 0) ? bias[m] : 0.f;

      {
        const u64* gp = prd + row * HH + cbase;
        float* Urow = U + row * KP + cbase;
        u64 va[8], vb[8];
        #pragma unroll
        for (int q = 0; q < 4; ++q) {       // pre-issue chunks 0..3
          va[q] = __hip_atomic_load(gp + 16 * q,
                                    __ATOMIC_RELAXED, __HIP_MEMORY_SCOPE_AGENT);
          vb[q] = __hip_atomic_load(gp + 16 * q + 8,
                                    __ATOMIC_RELAXED, __HIP_MEMORY_SCOPE_AGENT);
        }
        #pragma unroll
        for (int q = 0; q < 8; ++q) {
          // spin until this chunk's pair is fresh (rare after warm-up)
          while ((unsigned)(va[q] >> 32) < (unsigned)s ||
                 (unsigned)(vb[q] >> 32) < (unsigned)s) {
            __builtin_amdgcn_s_sleep(1);
            va[q] = __hip_atomic_load(gp + 16 * q,
                                      __ATOMIC_RELAXED, __HIP_MEMORY_SCOPE_AGENT);
            vb[q] = __hip_atomic_load(gp + 16 * q + 8,
                                      __ATOMIC_RELAXED, __HIP_MEMORY_SCOPE_AGENT);
          }
          Urow[16 * q]     = __uint_as_float((unsigned)va[q]);
          Urow[16 * q + 8] = __uint_as_float((unsigned)vb[q]);
          if (q + 4 < 8) {                  // issue chunk q+4 tag loads
            va[q + 4] = __hip_atomic_load(gp + 16 * (q + 4),
                                          __ATOMIC_RELAXED, __HIP_MEMORY_SCOPE_AGENT);
            vb[q + 4] = __hip_atomic_load(gp + 16 * (q + 4) + 8,
                                          __ATOMIC_RELAXED, __HIP_MEMORY_SCOPE_AGENT);
          }
          asm volatile("" ::: "memory");    // keep ds_writes before the reads
          // FMA on chunk q: 8 rows x 4 cols x 4 gate types
          #pragma unroll
          for (int b = 0; b < 8; ++b) {
            const f4v u = *(const f4v*)&U[b * KP + w * 128 + 16 * q + 4 * kap];
            #pragma unroll
            for (int m = 0; m < 4; ++m)
              acc[m][b] += u[0] * wv[m][q][0] + u[1] * wv[m][q][1]
                         + u[2] * wv[m][q][2] + u[3] * wv[m][q][3];
          }
        }
      }
      // x-part (same-wave LDS writes, compiler-ordered)
      #pragma unroll
      for (int b = 0; b < 8; ++b) {
        const float2 ux = *(const float2*)&U[b * KP + HH + w * 8 + 2 * kap];
        #pragma unroll
        for (int m = 0; m < 4; ++m)
          acc[m][b] += ux.x * wx[m].x + ux.y * wx[m].y;
      }
      {
        float* Gw = Grp + ks * GPL + gt;
        #pragma unroll
        for (int b = 0; b < 8; ++b)
          #pragma unroll
          for (int m = 0; m < 4; ++m)
            Gw[b * GRS + m * 16] = acc[m][b];
      }

      // ---- decoder out-projection partials (wave-private U cols, pre-update h) ----
      if (phase) {
        const float* wrow = Wo + gb * HH + w * 128 + sub * 16;
        const float* urow = U + row * KP + w * 128 + sub * 16;
        float pj = 0.f;
        #pragma unroll
        for (int k = 0; k < 16; k += 4) {
          const f4v wvv = *(const f4v*)(wrow + k);
          const f4v uvv = *(const f4v*)(urow + k);
          pj += uvv[0] * wvv[0] + uvv[1] * wvv[1] + uvv[2] * wvv[2] + uvv[3] * wvv[3];
        }
        OPp[w * 64 + lane] = pj;
      }
      __syncthreads();   // BAR A (the only barrier): Gr/OPW complete

      // ---- reduce 16 K-split partials, activations, update, tagged publish ----
      if (upd) {
        const float* g0 = Grp + ub * GRS + ujl;
        float si = 0.f, sf = 0.f, sg = 0.f, so = 0.f;
        #pragma unroll
        for (int q = 0; q < 16; ++q) {
          const float* g = g0 + q * GPL;
          si += g[0]; sf += g[16]; sg += g[32]; so += g[48];
        }
        const float c2 = sigmf(sf) * c_reg + sigmf(si) * tanhfast(sg);
        const float h2 = sigmf(so) * tanhfast(c2);
        c_reg = c2;
        const u64 pk = ((u64)(unsigned)(s + 1) << 32) | (u64)__float_as_uint(h2);
        __hip_atomic_store(&pwr[ub * HH + j0 + ujl], pk,
                           __ATOMIC_RELAXED, __HIP_MEMORY_SCOPE_AGENT);
      }
      // ---- out-projection reduce by 8 idle wave-3 threads ----
      if (phase && tid >= 192 && tid < 200) {
        const int b = tid - 192;
        float sm = 0.f;
        #pragma unroll
        for (int w2 = 0; w2 < 4; ++w2)
          #pragma unroll
          for (int k = 0; k < 8; ++k)
            sm += OPp[w2 * 64 + b * 8 + k];
        out[((b0 + b) * TT + t) * FF + gb] = sm + bo[gb];
      }
      // NO BAR B: Gr/OPW are parity-buffered; U is wave-private; the single
      // barrier bounds intra-block skew to one step = the parity depth.
    }
    if (phase == 0)  // encoder done: swap register weights to decoder
      load_w(dWih, dWhh, dbih, dbhh, j0, w, kap, gt, wv, wx, bias);
  }
}

extern "C" void kernel_launch(void* const* d_in, const int* in_sizes, int n_in,
                              void* d_out, int out_size, void* d_ws, size_t ws_size,
                              hipStream_t stream) {
  const float* x    = (const float*)d_in[0];
  const float* eWih = (const float*)d_in[1];   // enc_Wih0 [2048,32]
  const float* eWhh = (const float*)d_in[2];   // enc_Whh0 [2048,512]
  const float* ebih = (const float*)d_in[3];
  const float* ebhh = (const float*)d_in[4];
  // d_in[5..8] enc layer 1: dead (only feeds dead decoder layer 1)
  const float* dWih = (const float*)d_in[9];   // dec_Wih0
  const float* dWhh = (const float*)d_in[10];  // dec_Whh0
  const float* dbih = (const float*)d_in[11];
  const float* dbhh = (const float*)d_in[12];
  // d_in[13..16] dec layer 1: dead (hB/cB never reach outs)
  const float* Wo   = (const float*)d_in[17];  // [32,512]
  const float* bo   = (const float*)d_in[18];  // [32]
  float* out = (float*)d_out;

  u64* pubbuf = (u64*)d_ws;                    // [2][PODS][BT][HH] tagged h

  hipFuncSetAttribute(reinterpret_cast<const void*>(lstm_ae_kernel),
                      hipFuncAttributeMaxDynamicSharedMemorySize, LDS_BYTES);

  init_ws_kernel<<<dim3((PUB_U64 + NTHR - 1) / NTHR), dim3(NTHR), 0, stream>>>(pubbuf);
  lstm_ae_kernel<<<dim3(NBLK), dim3(NTHR), LDS_BYTES, stream>>>(
      x, eWih, eWhh, ebih, ebhh, dWih, dWhh, dbih, dbhh, Wo, bo,
      out, pubbuf);
}